// Round 13
// baseline (323.602 us; speedup 1.0000x reference)
//
#include <hip/hip_runtime.h>
#include <hip/hip_bf16.h>

#define NN 200000
#define NE 3200000
#define NG 4096
#define INC 78
#define C1 64
#define C2 128
#define ODIM 128

#define BSZ 256     // nodes per bucket
#define NBKT 782    // ceil(NN/BSZ)
#define NBLK 1568   // binning blocks (6+/CU -> occupancy fix; was 392)
#define EPB 2041    // ceil(NE/NBLK)
#define CAP 8192    // padded per-bucket capacity (mean 4092, sigma ~64 -> 64 sigma)

using bf16 = __hip_bfloat16;
typedef __attribute__((ext_vector_type(8))) short bf16x8;
typedef __attribute__((ext_vector_type(4))) float f32x4;

static inline size_t alignup(size_t x) { return (x + 255) & ~size_t(255); }

__device__ __forceinline__ float bflo(unsigned u) { return __uint_as_float(u << 16); }
__device__ __forceinline__ float bfhi(unsigned u) { return __uint_as_float(u & 0xffff0000u); }
__device__ __forceinline__ unsigned short f2bf(float f) {
    __hip_bfloat16 h = __float2bfloat16(f);
    return *reinterpret_cast<unsigned short*>(&h);
}

// ---------- single-pass binning, histogram-only LDS (pass 2 re-reads from L2) ----------
__global__ __launch_bounds__(256) void binsort_kernel(const int* __restrict__ src,
                                                      const int* __restrict__ dst,
                                                      int* __restrict__ gcursor,
                                                      unsigned* __restrict__ ebuf) {
    __shared__ int lh[NBKT];
    for (int j = threadIdx.x; j < NBKT; j += 256) lh[j] = 0;
    __syncthreads();
    int e0 = blockIdx.x * EPB;
    int e1 = e0 + EPB; if (e1 > NE) e1 = NE;
    for (int e = e0 + threadIdx.x; e < e1; e += 256)
        atomicAdd(&lh[((unsigned)dst[e]) >> 8], 1);
    __syncthreads();
    for (int j = threadIdx.x; j < NBKT; j += 256) {
        int c = lh[j];
        lh[j] = (c > 0) ? atomicAdd(&gcursor[j], c) : 0;
    }
    __syncthreads();
    for (int e = e0 + threadIdx.x; e < e1; e += 256) {
        int d = dst[e];                  // L2-hot re-read
        int s = src[e];
        int b = ((unsigned)d) >> 8;
        int off = atomicAdd(&lh[b], 1);
        if (off < CAP) ebuf[(size_t)b * CAP + off] = ((unsigned)s << 8) | (unsigned)(d & 255);
    }
}

// ---------- per-bucket: folded bucket-scan + degrees + dinv + rs + dense CSR ----------
__global__ __launch_bounds__(256) void degcsr_kernel(
    const unsigned* __restrict__ ebuf, const int* __restrict__ gcursor,
    int* __restrict__ rs, float* __restrict__ dinv, unsigned* __restrict__ csr) {
    __shared__ int cnt[BSZ];
    __shared__ int pfx[BSZ];
    __shared__ int seg[BSZ];
    __shared__ int gc[NBKT];
    __shared__ unsigned recs[CAP];
    __shared__ int s0_sh;
    int b = blockIdx.x;
    int t = threadIdx.x;
    for (int j = t; j < NBKT; j += 256) gc[j] = gcursor[j];
    __syncthreads();
    // segmented scan of gc to get dense bucket start s0 = sum gc[0..b)
    int ssum = 0;
    #pragma unroll
    for (int k = 0; k < 4; ++k) { int j = t * 4 + k; if (j < NBKT) ssum += gc[j]; }
    seg[t] = ssum;
    __syncthreads();
    for (int off = 1; off < 256; off <<= 1) {
        int v = (t >= off) ? seg[t - off] : 0;
        __syncthreads();
        seg[t] += v;
        __syncthreads();
    }
    if (t == 0) {
        int tb = b >> 2;
        int ex = (tb > 0) ? seg[tb - 1] : 0;
        for (int j = tb * 4; j < b; ++j) ex += gc[j];
        s0_sh = ex;
    }
    int nrec = gc[b]; if (nrec > CAP) nrec = CAP;
    cnt[t] = 0;
    for (int i = t; i < nrec; i += 256) recs[i] = ebuf[(size_t)b * CAP + i];
    __syncthreads();
    int s0 = s0_sh;
    for (int i = t; i < nrec; i += 256)
        atomicAdd(&cnt[recs[i] & 255], 1);
    __syncthreads();
    int v = cnt[t];
    pfx[t] = v;
    __syncthreads();
    for (int off = 1; off < 256; off <<= 1) {
        int u = (t >= off) ? pfx[t - off] : 0;
        __syncthreads();
        pfx[t] += u;
        __syncthreads();
    }
    int myrs = s0 + pfx[t] - v;   // dense exclusive
    int node = b * BSZ + t;
    if (node < NN) {
        rs[node] = myrs;
        dinv[node] = rsqrtf((float)v + 1.0f);
    }
    if (node == NN) rs[NN] = NE;
    __syncthreads();
    cnt[t] = 0;        // reuse as cursor
    pfx[t] = myrs;     // row base per local node
    __syncthreads();
    for (int i = t; i < nrec; i += 256) {
        unsigned rec = recs[i];
        int nl = rec & 255;
        int pos = atomicAdd(&cnt[nl], 1);
        csr[pfx[nl] + pos] = rec >> 8;
    }
}

// ---------- gemm1: hw1s = bf16(dinv[n]*(x @ W1)); x->bf16 LDS, W1 f32 LDS (stride 65) ----------
__global__ __launch_bounds__(256) void gemm1_mfma(const float* __restrict__ x,
                                                  const float* __restrict__ W1,
                                                  const float* __restrict__ dinv,
                                                  unsigned short* __restrict__ hw1s) {
    __shared__ unsigned short xs[64 * INC];   // 9984 B bf16
    __shared__ float w1s[INC * 65];           // 20280 B f32, padded stride
    for (int i = threadIdx.x; i < (INC * C1) / 2; i += 256) {
        float2 w = ((const float2*)W1)[i];
        int k = (i * 2) / C1, c = (i * 2) % C1;
        w1s[k * 65 + c] = w.x;
        w1s[k * 65 + c + 1] = w.y;
    }
    const float2* gx = (const float2*)(x + (size_t)blockIdx.x * 64 * INC);
    for (int i = threadIdx.x; i < (64 * INC) / 2; i += 256) {
        float2 v = gx[i];
        unsigned pk = (unsigned)f2bf(v.x) | ((unsigned)f2bf(v.y) << 16);
        *(unsigned*)(xs + i * 2) = pk;
    }
    __syncthreads();
    int wave = threadIdx.x >> 6, lane = threadIdx.x & 63;
    int r = lane & 15, kg = lane >> 4;
    int lrow = wave * 16 + r;
    int row0 = blockIdx.x * 64 + wave * 16;
    bf16x8 a[3];
    #pragma unroll
    for (int t = 0; t < 3; ++t) {
        union { bf16x8 v; unsigned short u[8]; } tmp;
        #pragma unroll
        for (int j = 0; j < 8; ++j) {
            int k = t * 32 + kg * 8 + j;
            tmp.u[j] = (k < INC) ? xs[lrow * INC + k] : (unsigned short)0;
        }
        a[t] = tmp.v;
    }
    float dsc[4];
    #pragma unroll
    for (int i = 0; i < 4; ++i) dsc[i] = dinv[row0 + kg * 4 + i];
    #pragma unroll
    for (int nt = 0; nt < 4; ++nt) {
        int c = nt * 16 + r;
        bf16x8 bf[3];
        #pragma unroll
        for (int t = 0; t < 3; ++t) {
            union { bf16x8 v; unsigned short u[8]; } tb;
            #pragma unroll
            for (int j = 0; j < 8; ++j) {
                int k = t * 32 + kg * 8 + j;
                tb.u[j] = (k < INC) ? f2bf(w1s[k * 65 + c]) : (unsigned short)0;
            }
            bf[t] = tb.v;
        }
        f32x4 acc = {0.f, 0.f, 0.f, 0.f};
        acc = __builtin_amdgcn_mfma_f32_16x16x32_bf16(a[0], bf[0], acc, 0, 0, 0);
        acc = __builtin_amdgcn_mfma_f32_16x16x32_bf16(a[1], bf[1], acc, 0, 0, 0);
        acc = __builtin_amdgcn_mfma_f32_16x16x32_bf16(a[2], bf[2], acc, 0, 0, 0);
        unsigned short* cb = hw1s + (size_t)(row0 + kg * 4) * C1 + c;
        #pragma unroll
        for (int i = 0; i < 4; ++i) cb[(size_t)i * C1] = f2bf(acc[i] * dsc[i]);
    }
}

// ---------- gather core: 8-lane group, 16B row fragments, unroll 4 ----------
__device__ __forceinline__ void gather_node(
    const unsigned* __restrict__ csr, int start, int len,
    const unsigned short* __restrict__ vin, int c0,
    float& a0, float& a1, float& a2, float& a3,
    float& a4, float& a5, float& a6, float& a7) {
    int e = 0;
    for (; e + 4 <= len; e += 4) {
        unsigned s0 = csr[start + e + 0];
        unsigned s1 = csr[start + e + 1];
        unsigned s2 = csr[start + e + 2];
        unsigned s3 = csr[start + e + 3];
        uint4 r0 = *(const uint4*)(vin + (size_t)s0 * 64 + c0);
        uint4 r1 = *(const uint4*)(vin + (size_t)s1 * 64 + c0);
        uint4 r2 = *(const uint4*)(vin + (size_t)s2 * 64 + c0);
        uint4 r3 = *(const uint4*)(vin + (size_t)s3 * 64 + c0);
        a0 += (bflo(r0.x) + bflo(r1.x)) + (bflo(r2.x) + bflo(r3.x));
        a1 += (bfhi(r0.x) + bfhi(r1.x)) + (bfhi(r2.x) + bfhi(r3.x));
        a2 += (bflo(r0.y) + bflo(r1.y)) + (bflo(r2.y) + bflo(r3.y));
        a3 += (bfhi(r0.y) + bfhi(r1.y)) + (bfhi(r2.y) + bfhi(r3.y));
        a4 += (bflo(r0.z) + bflo(r1.z)) + (bflo(r2.z) + bflo(r3.z));
        a5 += (bfhi(r0.z) + bfhi(r1.z)) + (bfhi(r2.z) + bfhi(r3.z));
        a6 += (bflo(r0.w) + bflo(r1.w)) + (bflo(r2.w) + bflo(r3.w));
        a7 += (bfhi(r0.w) + bfhi(r1.w)) + (bfhi(r2.w) + bfhi(r3.w));
    }
    for (; e < len; ++e) {
        unsigned s = csr[start + e];
        uint4 ra = *(const uint4*)(vin + (size_t)s * 64 + c0);
        a0 += bflo(ra.x); a1 += bfhi(ra.x);
        a2 += bflo(ra.y); a3 += bfhi(ra.y);
        a4 += bflo(ra.z); a5 += bfhi(ra.z);
        a6 += bflo(ra.w); a7 += bfhi(ra.w);
    }
}

// ---------- aggregate kernels (8 lanes/node, 32 nodes/block) ----------
// EP=1: out = bf16(relu(dinv*(acc+self) + b1) * dinv);  EP=2: out = bf16(dinv*(acc+self))
template <int EP>
__global__ __launch_bounds__(256) void agg_csr_kernel(
    const unsigned* __restrict__ csr, const int* __restrict__ rs,
    const float* __restrict__ dinv, const unsigned short* __restrict__ vin,
    const float* __restrict__ bias, unsigned short* __restrict__ vout) {
    int node = blockIdx.x * 32 + (threadIdx.x >> 3);
    int l = threadIdx.x & 7;
    int c0 = l * 8;
    int start = rs[node], len = rs[node + 1] - start;
    float a0 = 0.f, a1 = 0.f, a2 = 0.f, a3 = 0.f, a4 = 0.f, a5 = 0.f, a6 = 0.f, a7 = 0.f;
    gather_node(csr, start, len, vin, c0, a0, a1, a2, a3, a4, a5, a6, a7);
    uint4 sv = *(const uint4*)(vin + (size_t)node * 64 + c0);
    a0 += bflo(sv.x); a1 += bfhi(sv.x);
    a2 += bflo(sv.y); a3 += bfhi(sv.y);
    a4 += bflo(sv.z); a5 += bfhi(sv.z);
    a6 += bflo(sv.w); a7 += bfhi(sv.w);
    float d = dinv[node];
    if (EP == 1) {
        a0 = fmaxf(a0 * d + bias[c0 + 0], 0.f) * d;
        a1 = fmaxf(a1 * d + bias[c0 + 1], 0.f) * d;
        a2 = fmaxf(a2 * d + bias[c0 + 2], 0.f) * d;
        a3 = fmaxf(a3 * d + bias[c0 + 3], 0.f) * d;
        a4 = fmaxf(a4 * d + bias[c0 + 4], 0.f) * d;
        a5 = fmaxf(a5 * d + bias[c0 + 5], 0.f) * d;
        a6 = fmaxf(a6 * d + bias[c0 + 6], 0.f) * d;
        a7 = fmaxf(a7 * d + bias[c0 + 7], 0.f) * d;
    } else {
        a0 *= d; a1 *= d; a2 *= d; a3 *= d; a4 *= d; a5 *= d; a6 *= d; a7 *= d;
    }
    uint4 o;
    o.x = (unsigned)f2bf(a0) | ((unsigned)f2bf(a1) << 16);
    o.y = (unsigned)f2bf(a2) | ((unsigned)f2bf(a3) << 16);
    o.z = (unsigned)f2bf(a4) | ((unsigned)f2bf(a5) << 16);
    o.w = (unsigned)f2bf(a6) | ((unsigned)f2bf(a7) << 16);
    *(uint4*)(vout + (size_t)node * 64 + c0) = o;
}

// ---------- gemm2: h2 = bf16(relu(aggH @ W2 + b2)); W2 f32 LDS (stride 129) ----------
__global__ __launch_bounds__(256) void gemm2_mfma(const unsigned short* __restrict__ aggH,
                                                  const float* __restrict__ W2,
                                                  const float* __restrict__ b2,
                                                  unsigned short* __restrict__ h2) {
    __shared__ float w2s[C1 * 129];   // 33024 B
    for (int i = threadIdx.x; i < (C1 * C2) / 2; i += 256) {
        float2 w = ((const float2*)W2)[i];
        int k = (i * 2) >> 7, c = (i * 2) & 127;
        w2s[k * 129 + c] = w.x;
        w2s[k * 129 + c + 1] = w.y;
    }
    __syncthreads();
    int wave = threadIdx.x >> 6, lane = threadIdx.x & 63;
    int r = lane & 15, kg = lane >> 4;
    int row0 = blockIdx.x * 64 + wave * 16;
    const unsigned short* arow = aggH + (size_t)(row0 + r) * 64 + kg * 8;
    bf16x8 a0 = *(const bf16x8*)(arow);
    bf16x8 a1 = *(const bf16x8*)(arow + 32);
    #pragma unroll
    for (int nt = 0; nt < 8; ++nt) {
        int col = nt * 16 + r;
        bf16x8 b0, b1;
        {
            union { bf16x8 v; unsigned short u[8]; } tb;
            #pragma unroll
            for (int j = 0; j < 8; ++j) tb.u[j] = f2bf(w2s[(kg * 8 + j) * 129 + col]);
            b0 = tb.v;
            #pragma unroll
            for (int j = 0; j < 8; ++j) tb.u[j] = f2bf(w2s[(32 + kg * 8 + j) * 129 + col]);
            b1 = tb.v;
        }
        f32x4 acc = {0.f, 0.f, 0.f, 0.f};
        acc = __builtin_amdgcn_mfma_f32_16x16x32_bf16(a0, b0, acc, 0, 0, 0);
        acc = __builtin_amdgcn_mfma_f32_16x16x32_bf16(a1, b1, acc, 0, 0, 0);
        float bb = b2[col];
        unsigned short* cb = h2 + (size_t)(row0 + kg * 4) * C2 + col;
        #pragma unroll
        for (int i = 0; i < 4; ++i) cb[(size_t)i * C2] = f2bf(fmaxf(acc[i] + bb, 0.f));
    }
}

// ---------- fused mean-pool + final FC ----------
__device__ __forceinline__ int lbound(const int* __restrict__ a, int n, int key) {
    int lo = 0, hi = n;
    while (lo < hi) {
        int mid = (lo + hi) >> 1;
        if (a[mid] < key) lo = mid + 1; else hi = mid;
    }
    return lo;
}

__global__ __launch_bounds__(256) void pool_fc_kernel(const unsigned short* __restrict__ h2,
                                                      const int* __restrict__ batch,
                                                      const float* __restrict__ fcw,
                                                      const float* __restrict__ fcb,
                                                      float* __restrict__ out) {
    __shared__ float ps[512];
    __shared__ float pr[128];
    int g = blockIdx.x;
    int lo = lbound(batch, NN, g);
    int hi = lbound(batch, NN, g + 1);
    int cnt = hi - lo;
    int rg = threadIdx.x >> 6;
    int p = threadIdx.x & 63;
    float s0 = 0.f, s1 = 0.f;
    for (int r = lo + rg; r < hi; r += 4) {
        unsigned v = *(const unsigned*)(h2 + (size_t)r * C2 + p * 2);
        s0 += bflo(v);
        s1 += bfhi(v);
    }
    ps[threadIdx.x * 2 + 0] = s0;
    ps[threadIdx.x * 2 + 1] = s1;
    __syncthreads();
    if (threadIdx.x < 64) {
        float inv = 1.0f / (float)((cnt > 0) ? cnt : 1);
        int t = threadIdx.x;
        float r0 = 0.f, r1 = 0.f;
        #pragma unroll
        for (int k = 0; k < 4; ++k) {
            r0 += ps[(k * 64 + t) * 2 + 0];
            r1 += ps[(k * 64 + t) * 2 + 1];
        }
        pr[2 * t + 0] = r0 * inv;
        pr[2 * t + 1] = r1 * inv;
    }
    __syncthreads();
    if (threadIdx.x < 128) {
        int o = threadIdx.x;
        float acc = fcb[o];
        #pragma unroll 8
        for (int k = 0; k < C2; ++k) acc += pr[k] * fcw[k * ODIM + o];
        out[(size_t)g * ODIM + o] = acc;
    }
}

extern "C" void kernel_launch(void* const* d_in, const int* in_sizes, int n_in,
                              void* d_out, int out_size, void* d_ws, size_t ws_size,
                              hipStream_t stream) {
    const float* x   = (const float*)d_in[0];
    const int*   ei  = (const int*)d_in[1];
    const int*   bat = (const int*)d_in[2];
    const float* W1  = (const float*)d_in[3];
    const float* b1  = (const float*)d_in[4];
    const float* W2  = (const float*)d_in[5];
    const float* b2  = (const float*)d_in[6];
    const float* fcw = (const float*)d_in[7];
    const float* fcb = (const float*)d_in[8];
    float* out = (float*)d_out;

    const int* src = ei;        // edge_index[0]
    const int* dst = ei + NE;   // edge_index[1]

    char* ws = (char*)d_ws;
    int* gcursor = (int*)ws;            ws += alignup((size_t)NBKT * 4);
    int* rs      = (int*)ws;            ws += alignup((size_t)(NN + 1) * 4);
    float* dinv  = (float*)ws;          ws += alignup((size_t)NN * 4);
    unsigned short* hw1s = (unsigned short*)ws; ws += alignup((size_t)NN * C1 * 2);
    unsigned short* aggH = hw1s;        // reuse: hw1s dead after agg_csr<1>
    // h2 (51.2MB) aliases [ebuf 25.6 | csr 12.8 | first 12.8 of h1s] -- all dead before gemm2
    unsigned* ebuf = (unsigned*)ws;     ws += alignup((size_t)NBKT * CAP * 4);
    unsigned* csr  = (unsigned*)ws;     ws += alignup((size_t)NE * 4);
    unsigned short* h1s = (unsigned short*)ws;  ws += alignup((size_t)NN * C1 * 2);
    unsigned short* h2 = (unsigned short*)ebuf;
    // total ~91 MB

    // ---- single-pass binning into padded bucket regions ----
    hipMemsetAsync(gcursor, 0, (size_t)NBKT * 4, stream);
    binsort_kernel<<<NBLK, 256, 0, stream>>>(src, dst, gcursor, ebuf);

    // ---- bucket scan (folded) + degrees + dinv + rs + dense CSR ----
    degcsr_kernel<<<NBKT, 256, 0, stream>>>(ebuf, gcursor, rs, dinv, csr);

    // ---- layer 1: staged MFMA GEMM (in-kernel W1 conversion) then gather ----
    gemm1_mfma<<<NN / 64, 256, 0, stream>>>(x, W1, dinv, hw1s);
    agg_csr_kernel<1><<<NN / 32, 256, 0, stream>>>(csr, rs, dinv, hw1s, b1, h1s);

    // ---- layer 2: aggregate first (linearity), then GEMM + relu -> h2 ----
    agg_csr_kernel<2><<<NN / 32, 256, 0, stream>>>(csr, rs, dinv, h1s, b1, aggH);
    gemm2_mfma<<<NN / 64, 256, 0, stream>>>(aggH, W2, b2, h2);

    // ---- fused mean-pool + FC ----
    pool_fc_kernel<<<NG, 256, 0, stream>>>(h2, bat, fcw, fcb, out);
}

// Round 14
// 276.612 us; speedup vs baseline: 1.1699x; 1.1699x over previous
//
#include <hip/hip_runtime.h>
#include <hip/hip_bf16.h>

#define NN 200000
#define NE 3200000
#define NG 4096
#define INC 78
#define C1 64
#define C2 128
#define ODIM 128

#define BSZ 256     // nodes per bucket
#define NBKT 782    // ceil(NN/BSZ)
#define NBLK 392    // binning blocks (longer runs -> coherent ebuf writes; r13 showed 1568 regresses)
#define EPB 8164    // ceil(NE/NBLK)
#define CAP 8192    // padded per-bucket capacity (mean 4092, sigma ~64 -> 64 sigma)

using bf16 = __hip_bfloat16;
typedef __attribute__((ext_vector_type(8))) short bf16x8;
typedef __attribute__((ext_vector_type(4))) float f32x4;

static inline size_t alignup(size_t x) { return (x + 255) & ~size_t(255); }

__device__ __forceinline__ float bflo(unsigned u) { return __uint_as_float(u << 16); }
__device__ __forceinline__ float bfhi(unsigned u) { return __uint_as_float(u & 0xffff0000u); }
__device__ __forceinline__ unsigned short f2bf(float f) {
    __hip_bfloat16 h = __float2bfloat16(f);
    return *reinterpret_cast<unsigned short*>(&h);
}

// ---------- single-pass binning with LDS record staging (r11 variant: best measured) ----------
__global__ __launch_bounds__(256) void binsort_kernel(const int* __restrict__ src,
                                                      const int* __restrict__ dst,
                                                      int* __restrict__ gcursor,
                                                      unsigned* __restrict__ ebuf) {
    __shared__ unsigned recs[EPB];            // 32656 B
    __shared__ unsigned short bkts[EPB];      // 16328 B
    __shared__ int lh[NBKT];                  // 3128 B
    for (int j = threadIdx.x; j < NBKT; j += 256) lh[j] = 0;
    __syncthreads();
    int e0 = blockIdx.x * EPB;
    int e1 = e0 + EPB; if (e1 > NE) e1 = NE;
    int n = e1 - e0;
    for (int i = threadIdx.x; i < n; i += 256) {
        int d = dst[e0 + i];
        int s = src[e0 + i];
        recs[i] = ((unsigned)s << 8) | (unsigned)(d & 255);
        int b = ((unsigned)d) >> 8;
        bkts[i] = (unsigned short)b;
        atomicAdd(&lh[b], 1);
    }
    __syncthreads();
    // reserve a run per non-empty bucket; lh becomes the block's running cursor
    for (int j = threadIdx.x; j < NBKT; j += 256) {
        int c = lh[j];
        lh[j] = (c > 0) ? atomicAdd(&gcursor[j], c) : 0;
    }
    __syncthreads();
    for (int i = threadIdx.x; i < n; i += 256) {
        int b = bkts[i];
        int off = atomicAdd(&lh[b], 1);
        if (off < CAP) ebuf[(size_t)b * CAP + off] = recs[i];
    }
}

// ---------- per-bucket: folded bucket-scan + degrees + dinv + rs + dense CSR ----------
__global__ __launch_bounds__(256) void degcsr_kernel(
    const unsigned* __restrict__ ebuf, const int* __restrict__ gcursor,
    int* __restrict__ rs, float* __restrict__ dinv, unsigned* __restrict__ csr) {
    __shared__ int cnt[BSZ];
    __shared__ int pfx[BSZ];
    __shared__ int seg[BSZ];
    __shared__ int gc[NBKT];
    __shared__ unsigned recs[CAP];
    __shared__ int s0_sh;
    int b = blockIdx.x;
    int t = threadIdx.x;
    for (int j = t; j < NBKT; j += 256) gc[j] = gcursor[j];
    __syncthreads();
    // segmented scan of gc to get dense bucket start s0 = sum gc[0..b)
    int ssum = 0;
    #pragma unroll
    for (int k = 0; k < 4; ++k) { int j = t * 4 + k; if (j < NBKT) ssum += gc[j]; }
    seg[t] = ssum;
    __syncthreads();
    for (int off = 1; off < 256; off <<= 1) {
        int v = (t >= off) ? seg[t - off] : 0;
        __syncthreads();
        seg[t] += v;
        __syncthreads();
    }
    if (t == 0) {
        int tb = b >> 2;
        int ex = (tb > 0) ? seg[tb - 1] : 0;
        for (int j = tb * 4; j < b; ++j) ex += gc[j];
        s0_sh = ex;
    }
    int nrec = gc[b]; if (nrec > CAP) nrec = CAP;
    cnt[t] = 0;
    for (int i = t; i < nrec; i += 256) recs[i] = ebuf[(size_t)b * CAP + i];
    __syncthreads();
    int s0 = s0_sh;
    for (int i = t; i < nrec; i += 256)
        atomicAdd(&cnt[recs[i] & 255], 1);
    __syncthreads();
    int v = cnt[t];
    pfx[t] = v;
    __syncthreads();
    for (int off = 1; off < 256; off <<= 1) {
        int u = (t >= off) ? pfx[t - off] : 0;
        __syncthreads();
        pfx[t] += u;
        __syncthreads();
    }
    int myrs = s0 + pfx[t] - v;   // dense exclusive
    int node = b * BSZ + t;
    if (node < NN) {
        rs[node] = myrs;
        dinv[node] = rsqrtf((float)v + 1.0f);
    }
    if (node == NN) rs[NN] = NE;
    __syncthreads();
    cnt[t] = 0;        // reuse as cursor
    pfx[t] = myrs;     // row base per local node
    __syncthreads();
    for (int i = t; i < nrec; i += 256) {
        unsigned rec = recs[i];
        int nl = rec & 255;
        int pos = atomicAdd(&cnt[nl], 1);
        csr[pfx[nl] + pos] = rec >> 8;
    }
}

// ---------- gemm1: hw1s = bf16(dinv[n]*(x @ W1)); x->bf16 LDS, W1 f32 LDS (stride 65) ----------
__global__ __launch_bounds__(256) void gemm1_mfma(const float* __restrict__ x,
                                                  const float* __restrict__ W1,
                                                  const float* __restrict__ dinv,
                                                  unsigned short* __restrict__ hw1s) {
    __shared__ unsigned short xs[64 * INC];   // 9984 B bf16
    __shared__ float w1s[INC * 65];           // 20280 B f32, padded stride
    for (int i = threadIdx.x; i < (INC * C1) / 2; i += 256) {
        float2 w = ((const float2*)W1)[i];
        int k = (i * 2) / C1, c = (i * 2) % C1;
        w1s[k * 65 + c] = w.x;
        w1s[k * 65 + c + 1] = w.y;
    }
    const float2* gx = (const float2*)(x + (size_t)blockIdx.x * 64 * INC);
    for (int i = threadIdx.x; i < (64 * INC) / 2; i += 256) {
        float2 v = gx[i];
        unsigned pk = (unsigned)f2bf(v.x) | ((unsigned)f2bf(v.y) << 16);
        *(unsigned*)(xs + i * 2) = pk;
    }
    __syncthreads();
    int wave = threadIdx.x >> 6, lane = threadIdx.x & 63;
    int r = lane & 15, kg = lane >> 4;
    int lrow = wave * 16 + r;
    int row0 = blockIdx.x * 64 + wave * 16;
    bf16x8 a[3];
    #pragma unroll
    for (int t = 0; t < 3; ++t) {
        union { bf16x8 v; unsigned short u[8]; } tmp;
        #pragma unroll
        for (int j = 0; j < 8; ++j) {
            int k = t * 32 + kg * 8 + j;
            tmp.u[j] = (k < INC) ? xs[lrow * INC + k] : (unsigned short)0;
        }
        a[t] = tmp.v;
    }
    float dsc[4];
    #pragma unroll
    for (int i = 0; i < 4; ++i) dsc[i] = dinv[row0 + kg * 4 + i];
    #pragma unroll
    for (int nt = 0; nt < 4; ++nt) {
        int c = nt * 16 + r;
        bf16x8 bf[3];
        #pragma unroll
        for (int t = 0; t < 3; ++t) {
            union { bf16x8 v; unsigned short u[8]; } tb;
            #pragma unroll
            for (int j = 0; j < 8; ++j) {
                int k = t * 32 + kg * 8 + j;
                tb.u[j] = (k < INC) ? f2bf(w1s[k * 65 + c]) : (unsigned short)0;
            }
            bf[t] = tb.v;
        }
        f32x4 acc = {0.f, 0.f, 0.f, 0.f};
        acc = __builtin_amdgcn_mfma_f32_16x16x32_bf16(a[0], bf[0], acc, 0, 0, 0);
        acc = __builtin_amdgcn_mfma_f32_16x16x32_bf16(a[1], bf[1], acc, 0, 0, 0);
        acc = __builtin_amdgcn_mfma_f32_16x16x32_bf16(a[2], bf[2], acc, 0, 0, 0);
        unsigned short* cb = hw1s + (size_t)(row0 + kg * 4) * C1 + c;
        #pragma unroll
        for (int i = 0; i < 4; ++i) cb[(size_t)i * C1] = f2bf(acc[i] * dsc[i]);
    }
}

// ---------- gather core: 8-lane group, 16B row fragments, unroll 4 ----------
__device__ __forceinline__ void gather_node(
    const unsigned* __restrict__ csr, int start, int len,
    const unsigned short* __restrict__ vin, int c0,
    float& a0, float& a1, float& a2, float& a3,
    float& a4, float& a5, float& a6, float& a7) {
    int e = 0;
    for (; e + 4 <= len; e += 4) {
        unsigned s0 = csr[start + e + 0];
        unsigned s1 = csr[start + e + 1];
        unsigned s2 = csr[start + e + 2];
        unsigned s3 = csr[start + e + 3];
        uint4 r0 = *(const uint4*)(vin + (size_t)s0 * 64 + c0);
        uint4 r1 = *(const uint4*)(vin + (size_t)s1 * 64 + c0);
        uint4 r2 = *(const uint4*)(vin + (size_t)s2 * 64 + c0);
        uint4 r3 = *(const uint4*)(vin + (size_t)s3 * 64 + c0);
        a0 += (bflo(r0.x) + bflo(r1.x)) + (bflo(r2.x) + bflo(r3.x));
        a1 += (bfhi(r0.x) + bfhi(r1.x)) + (bfhi(r2.x) + bfhi(r3.x));
        a2 += (bflo(r0.y) + bflo(r1.y)) + (bflo(r2.y) + bflo(r3.y));
        a3 += (bfhi(r0.y) + bfhi(r1.y)) + (bfhi(r2.y) + bfhi(r3.y));
        a4 += (bflo(r0.z) + bflo(r1.z)) + (bflo(r2.z) + bflo(r3.z));
        a5 += (bfhi(r0.z) + bfhi(r1.z)) + (bfhi(r2.z) + bfhi(r3.z));
        a6 += (bflo(r0.w) + bflo(r1.w)) + (bflo(r2.w) + bflo(r3.w));
        a7 += (bfhi(r0.w) + bfhi(r1.w)) + (bfhi(r2.w) + bfhi(r3.w));
    }
    for (; e < len; ++e) {
        unsigned s = csr[start + e];
        uint4 ra = *(const uint4*)(vin + (size_t)s * 64 + c0);
        a0 += bflo(ra.x); a1 += bfhi(ra.x);
        a2 += bflo(ra.y); a3 += bfhi(ra.y);
        a4 += bflo(ra.z); a5 += bfhi(ra.z);
        a6 += bflo(ra.w); a7 += bfhi(ra.w);
    }
}

// ---------- aggregate kernels (8 lanes/node, 32 nodes/block) ----------
// EP=1: out = bf16(relu(dinv*(acc+self) + b1) * dinv);  EP=2: out = bf16(dinv*(acc+self))
template <int EP>
__global__ __launch_bounds__(256) void agg_csr_kernel(
    const unsigned* __restrict__ csr, const int* __restrict__ rs,
    const float* __restrict__ dinv, const unsigned short* __restrict__ vin,
    const float* __restrict__ bias, unsigned short* __restrict__ vout) {
    int node = blockIdx.x * 32 + (threadIdx.x >> 3);
    int l = threadIdx.x & 7;
    int c0 = l * 8;
    int start = rs[node], len = rs[node + 1] - start;
    float a0 = 0.f, a1 = 0.f, a2 = 0.f, a3 = 0.f, a4 = 0.f, a5 = 0.f, a6 = 0.f, a7 = 0.f;
    gather_node(csr, start, len, vin, c0, a0, a1, a2, a3, a4, a5, a6, a7);
    uint4 sv = *(const uint4*)(vin + (size_t)node * 64 + c0);
    a0 += bflo(sv.x); a1 += bfhi(sv.x);
    a2 += bflo(sv.y); a3 += bfhi(sv.y);
    a4 += bflo(sv.z); a5 += bfhi(sv.z);
    a6 += bflo(sv.w); a7 += bfhi(sv.w);
    float d = dinv[node];
    if (EP == 1) {
        a0 = fmaxf(a0 * d + bias[c0 + 0], 0.f) * d;
        a1 = fmaxf(a1 * d + bias[c0 + 1], 0.f) * d;
        a2 = fmaxf(a2 * d + bias[c0 + 2], 0.f) * d;
        a3 = fmaxf(a3 * d + bias[c0 + 3], 0.f) * d;
        a4 = fmaxf(a4 * d + bias[c0 + 4], 0.f) * d;
        a5 = fmaxf(a5 * d + bias[c0 + 5], 0.f) * d;
        a6 = fmaxf(a6 * d + bias[c0 + 6], 0.f) * d;
        a7 = fmaxf(a7 * d + bias[c0 + 7], 0.f) * d;
    } else {
        a0 *= d; a1 *= d; a2 *= d; a3 *= d; a4 *= d; a5 *= d; a6 *= d; a7 *= d;
    }
    uint4 o;
    o.x = (unsigned)f2bf(a0) | ((unsigned)f2bf(a1) << 16);
    o.y = (unsigned)f2bf(a2) | ((unsigned)f2bf(a3) << 16);
    o.z = (unsigned)f2bf(a4) | ((unsigned)f2bf(a5) << 16);
    o.w = (unsigned)f2bf(a6) | ((unsigned)f2bf(a7) << 16);
    *(uint4*)(vout + (size_t)node * 64 + c0) = o;
}

// ---------- gemm2: h2 = bf16(relu(aggH @ W2 + b2)); W2 f32 LDS (stride 129) ----------
__global__ __launch_bounds__(256) void gemm2_mfma(const unsigned short* __restrict__ aggH,
                                                  const float* __restrict__ W2,
                                                  const float* __restrict__ b2,
                                                  unsigned short* __restrict__ h2) {
    __shared__ float w2s[C1 * 129];   // 33024 B
    for (int i = threadIdx.x; i < (C1 * C2) / 2; i += 256) {
        float2 w = ((const float2*)W2)[i];
        int k = (i * 2) >> 7, c = (i * 2) & 127;
        w2s[k * 129 + c] = w.x;
        w2s[k * 129 + c + 1] = w.y;
    }
    __syncthreads();
    int wave = threadIdx.x >> 6, lane = threadIdx.x & 63;
    int r = lane & 15, kg = lane >> 4;
    int row0 = blockIdx.x * 64 + wave * 16;
    const unsigned short* arow = aggH + (size_t)(row0 + r) * 64 + kg * 8;
    bf16x8 a0 = *(const bf16x8*)(arow);
    bf16x8 a1 = *(const bf16x8*)(arow + 32);
    #pragma unroll
    for (int nt = 0; nt < 8; ++nt) {
        int col = nt * 16 + r;
        bf16x8 b0, b1;
        {
            union { bf16x8 v; unsigned short u[8]; } tb;
            #pragma unroll
            for (int j = 0; j < 8; ++j) tb.u[j] = f2bf(w2s[(kg * 8 + j) * 129 + col]);
            b0 = tb.v;
            #pragma unroll
            for (int j = 0; j < 8; ++j) tb.u[j] = f2bf(w2s[(32 + kg * 8 + j) * 129 + col]);
            b1 = tb.v;
        }
        f32x4 acc = {0.f, 0.f, 0.f, 0.f};
        acc = __builtin_amdgcn_mfma_f32_16x16x32_bf16(a0, b0, acc, 0, 0, 0);
        acc = __builtin_amdgcn_mfma_f32_16x16x32_bf16(a1, b1, acc, 0, 0, 0);
        float bb = b2[col];
        unsigned short* cb = h2 + (size_t)(row0 + kg * 4) * C2 + col;
        #pragma unroll
        for (int i = 0; i < 4; ++i) cb[(size_t)i * C2] = f2bf(fmaxf(acc[i] + bb, 0.f));
    }
}

// ---------- fused mean-pool + final FC ----------
__device__ __forceinline__ int lbound(const int* __restrict__ a, int n, int key) {
    int lo = 0, hi = n;
    while (lo < hi) {
        int mid = (lo + hi) >> 1;
        if (a[mid] < key) lo = mid + 1; else hi = mid;
    }
    return lo;
}

__global__ __launch_bounds__(256) void pool_fc_kernel(const unsigned short* __restrict__ h2,
                                                      const int* __restrict__ batch,
                                                      const float* __restrict__ fcw,
                                                      const float* __restrict__ fcb,
                                                      float* __restrict__ out) {
    __shared__ float ps[512];
    __shared__ float pr[128];
    int g = blockIdx.x;
    int lo = lbound(batch, NN, g);
    int hi = lbound(batch, NN, g + 1);
    int cnt = hi - lo;
    int rg = threadIdx.x >> 6;
    int p = threadIdx.x & 63;
    float s0 = 0.f, s1 = 0.f;
    for (int r = lo + rg; r < hi; r += 4) {
        unsigned v = *(const unsigned*)(h2 + (size_t)r * C2 + p * 2);
        s0 += bflo(v);
        s1 += bfhi(v);
    }
    ps[threadIdx.x * 2 + 0] = s0;
    ps[threadIdx.x * 2 + 1] = s1;
    __syncthreads();
    if (threadIdx.x < 64) {
        float inv = 1.0f / (float)((cnt > 0) ? cnt : 1);
        int t = threadIdx.x;
        float r0 = 0.f, r1 = 0.f;
        #pragma unroll
        for (int k = 0; k < 4; ++k) {
            r0 += ps[(k * 64 + t) * 2 + 0];
            r1 += ps[(k * 64 + t) * 2 + 1];
        }
        pr[2 * t + 0] = r0 * inv;
        pr[2 * t + 1] = r1 * inv;
    }
    __syncthreads();
    if (threadIdx.x < 128) {
        int o = threadIdx.x;
        float acc = fcb[o];
        #pragma unroll 8
        for (int k = 0; k < C2; ++k) acc += pr[k] * fcw[k * ODIM + o];
        out[(size_t)g * ODIM + o] = acc;
    }
}

extern "C" void kernel_launch(void* const* d_in, const int* in_sizes, int n_in,
                              void* d_out, int out_size, void* d_ws, size_t ws_size,
                              hipStream_t stream) {
    const float* x   = (const float*)d_in[0];
    const int*   ei  = (const int*)d_in[1];
    const int*   bat = (const int*)d_in[2];
    const float* W1  = (const float*)d_in[3];
    const float* b1  = (const float*)d_in[4];
    const float* W2  = (const float*)d_in[5];
    const float* b2  = (const float*)d_in[6];
    const float* fcw = (const float*)d_in[7];
    const float* fcb = (const float*)d_in[8];
    float* out = (float*)d_out;

    const int* src = ei;        // edge_index[0]
    const int* dst = ei + NE;   // edge_index[1]

    char* ws = (char*)d_ws;
    int* gcursor = (int*)ws;            ws += alignup((size_t)NBKT * 4);
    int* rs      = (int*)ws;            ws += alignup((size_t)(NN + 1) * 4);
    float* dinv  = (float*)ws;          ws += alignup((size_t)NN * 4);
    unsigned short* hw1s = (unsigned short*)ws; ws += alignup((size_t)NN * C1 * 2);
    unsigned short* aggH = hw1s;        // reuse: hw1s dead after agg_csr<1>
    // h2 (51.2MB) aliases [ebuf 25.6 | csr 12.8 | first 12.8 of h1s] -- all dead before gemm2
    unsigned* ebuf = (unsigned*)ws;     ws += alignup((size_t)NBKT * CAP * 4);
    unsigned* csr  = (unsigned*)ws;     ws += alignup((size_t)NE * 4);
    unsigned short* h1s = (unsigned short*)ws;  ws += alignup((size_t)NN * C1 * 2);
    unsigned short* h2 = (unsigned short*)ebuf;
    // total ~91 MB

    // ---- single-pass binning into padded bucket regions ----
    hipMemsetAsync(gcursor, 0, (size_t)NBKT * 4, stream);
    binsort_kernel<<<NBLK, 256, 0, stream>>>(src, dst, gcursor, ebuf);

    // ---- bucket scan (folded) + degrees + dinv + rs + dense CSR ----
    degcsr_kernel<<<NBKT, 256, 0, stream>>>(ebuf, gcursor, rs, dinv, csr);

    // ---- layer 1: staged MFMA GEMM (in-kernel W1 conversion) then gather ----
    gemm1_mfma<<<NN / 64, 256, 0, stream>>>(x, W1, dinv, hw1s);
    agg_csr_kernel<1><<<NN / 32, 256, 0, stream>>>(csr, rs, dinv, hw1s, b1, h1s);

    // ---- layer 2: aggregate first (linearity), then GEMM + relu -> h2 ----
    agg_csr_kernel<2><<<NN / 32, 256, 0, stream>>>(csr, rs, dinv, h1s, b1, aggH);
    gemm2_mfma<<<NN / 64, 256, 0, stream>>>(aggH, W2, b2, h2);

    // ---- fused mean-pool + FC ----
    pool_fc_kernel<<<NG, 256, 0, stream>>>(h2, bat, fcw, fcb, out);
}

// Round 15
// 272.830 us; speedup vs baseline: 1.1861x; 1.0139x over previous
//
#include <hip/hip_runtime.h>
#include <hip/hip_bf16.h>

#define NN 200000
#define NE 3200000
#define NG 4096
#define INC 78
#define C1 64
#define C2 128
#define ODIM 128

#define BSZ 256     // nodes per bucket
#define NBKT 782    // ceil(NN/BSZ)
#define NBLK 392    // binning blocks (10.4-record runs -> coherent ebuf writes)
#define EPB 8164    // ceil(NE/NBLK)
#define CAP 8192    // padded per-bucket capacity (mean 4092, sigma ~64 -> 64 sigma)
#define BTH 512     // binsort threads (24 waves/CU at 3 blocks/CU)

using bf16 = __hip_bfloat16;
typedef __attribute__((ext_vector_type(8))) short bf16x8;
typedef __attribute__((ext_vector_type(4))) float f32x4;

static inline size_t alignup(size_t x) { return (x + 255) & ~size_t(255); }

__device__ __forceinline__ float bflo(unsigned u) { return __uint_as_float(u << 16); }
__device__ __forceinline__ float bfhi(unsigned u) { return __uint_as_float(u & 0xffff0000u); }
__device__ __forceinline__ unsigned short f2bf(float f) {
    __hip_bfloat16 h = __float2bfloat16(f);
    return *reinterpret_cast<unsigned short*>(&h);
}

// ---------- single-pass binning with LDS record staging, 512 threads ----------
__global__ __launch_bounds__(BTH) void binsort_kernel(const int* __restrict__ src,
                                                      const int* __restrict__ dst,
                                                      int* __restrict__ gcursor,
                                                      unsigned* __restrict__ ebuf) {
    __shared__ unsigned recs[EPB];            // 32656 B
    __shared__ unsigned short bkts[EPB];      // 16328 B
    __shared__ int lh[NBKT];                  // 3128 B
    for (int j = threadIdx.x; j < NBKT; j += BTH) lh[j] = 0;
    __syncthreads();
    int e0 = blockIdx.x * EPB;
    int e1 = e0 + EPB; if (e1 > NE) e1 = NE;
    int n = e1 - e0;
    for (int i = threadIdx.x; i < n; i += BTH) {
        int d = dst[e0 + i];
        int s = src[e0 + i];
        recs[i] = ((unsigned)s << 8) | (unsigned)(d & 255);
        int b = ((unsigned)d) >> 8;
        bkts[i] = (unsigned short)b;
        atomicAdd(&lh[b], 1);
    }
    __syncthreads();
    // reserve a run per non-empty bucket; lh becomes the block's running cursor
    for (int j = threadIdx.x; j < NBKT; j += BTH) {
        int c = lh[j];
        lh[j] = (c > 0) ? atomicAdd(&gcursor[j], c) : 0;
    }
    __syncthreads();
    for (int i = threadIdx.x; i < n; i += BTH) {
        int b = bkts[i];
        int off = atomicAdd(&lh[b], 1);
        if (off < CAP) ebuf[(size_t)b * CAP + off] = recs[i];
    }
}

// ---------- per-bucket: folded bucket-scan + degrees + dinv + rs + dense CSR ----------
__global__ __launch_bounds__(256) void degcsr_kernel(
    const unsigned* __restrict__ ebuf, const int* __restrict__ gcursor,
    int* __restrict__ rs, float* __restrict__ dinv, unsigned* __restrict__ csr) {
    __shared__ int cnt[BSZ];
    __shared__ int pfx[BSZ];
    __shared__ int seg[BSZ];
    __shared__ int gc[NBKT];
    __shared__ unsigned recs[CAP];
    __shared__ int s0_sh;
    int b = blockIdx.x;
    int t = threadIdx.x;
    for (int j = t; j < NBKT; j += 256) gc[j] = gcursor[j];
    __syncthreads();
    // segmented scan of gc to get dense bucket start s0 = sum gc[0..b)
    int ssum = 0;
    #pragma unroll
    for (int k = 0; k < 4; ++k) { int j = t * 4 + k; if (j < NBKT) ssum += gc[j]; }
    seg[t] = ssum;
    __syncthreads();
    for (int off = 1; off < 256; off <<= 1) {
        int v = (t >= off) ? seg[t - off] : 0;
        __syncthreads();
        seg[t] += v;
        __syncthreads();
    }
    if (t == 0) {
        int tb = b >> 2;
        int ex = (tb > 0) ? seg[tb - 1] : 0;
        for (int j = tb * 4; j < b; ++j) ex += gc[j];
        s0_sh = ex;
    }
    int nrec = gc[b]; if (nrec > CAP) nrec = CAP;
    cnt[t] = 0;
    for (int i = t; i < nrec; i += 256) recs[i] = ebuf[(size_t)b * CAP + i];
    __syncthreads();
    int s0 = s0_sh;
    for (int i = t; i < nrec; i += 256)
        atomicAdd(&cnt[recs[i] & 255], 1);
    __syncthreads();
    int v = cnt[t];
    pfx[t] = v;
    __syncthreads();
    for (int off = 1; off < 256; off <<= 1) {
        int u = (t >= off) ? pfx[t - off] : 0;
        __syncthreads();
        pfx[t] += u;
        __syncthreads();
    }
    int myrs = s0 + pfx[t] - v;   // dense exclusive
    int node = b * BSZ + t;
    if (node < NN) {
        rs[node] = myrs;
        dinv[node] = rsqrtf((float)v + 1.0f);
    }
    if (node == NN) rs[NN] = NE;
    __syncthreads();
    cnt[t] = 0;        // reuse as cursor
    pfx[t] = myrs;     // row base per local node
    __syncthreads();
    for (int i = t; i < nrec; i += 256) {
        unsigned rec = recs[i];
        int nl = rec & 255;
        int pos = atomicAdd(&cnt[nl], 1);
        csr[pfx[nl] + pos] = rec >> 8;
    }
}

// ---------- gemm1: hw1s = bf16(dinv[n]*(x @ W1)); x->bf16 LDS, W1 f32 LDS (stride 65) ----------
__global__ __launch_bounds__(256) void gemm1_mfma(const float* __restrict__ x,
                                                  const float* __restrict__ W1,
                                                  const float* __restrict__ dinv,
                                                  unsigned short* __restrict__ hw1s) {
    __shared__ unsigned short xs[64 * INC];   // 9984 B bf16
    __shared__ float w1s[INC * 65];           // 20280 B f32, padded stride
    for (int i = threadIdx.x; i < (INC * C1) / 2; i += 256) {
        float2 w = ((const float2*)W1)[i];
        int k = (i * 2) / C1, c = (i * 2) % C1;
        w1s[k * 65 + c] = w.x;
        w1s[k * 65 + c + 1] = w.y;
    }
    const float2* gx = (const float2*)(x + (size_t)blockIdx.x * 64 * INC);
    for (int i = threadIdx.x; i < (64 * INC) / 2; i += 256) {
        float2 v = gx[i];
        unsigned pk = (unsigned)f2bf(v.x) | ((unsigned)f2bf(v.y) << 16);
        *(unsigned*)(xs + i * 2) = pk;
    }
    __syncthreads();
    int wave = threadIdx.x >> 6, lane = threadIdx.x & 63;
    int r = lane & 15, kg = lane >> 4;
    int lrow = wave * 16 + r;
    int row0 = blockIdx.x * 64 + wave * 16;
    bf16x8 a[3];
    #pragma unroll
    for (int t = 0; t < 3; ++t) {
        union { bf16x8 v; unsigned short u[8]; } tmp;
        #pragma unroll
        for (int j = 0; j < 8; ++j) {
            int k = t * 32 + kg * 8 + j;
            tmp.u[j] = (k < INC) ? xs[lrow * INC + k] : (unsigned short)0;
        }
        a[t] = tmp.v;
    }
    float dsc[4];
    #pragma unroll
    for (int i = 0; i < 4; ++i) dsc[i] = dinv[row0 + kg * 4 + i];
    #pragma unroll
    for (int nt = 0; nt < 4; ++nt) {
        int c = nt * 16 + r;
        bf16x8 bf[3];
        #pragma unroll
        for (int t = 0; t < 3; ++t) {
            union { bf16x8 v; unsigned short u[8]; } tb;
            #pragma unroll
            for (int j = 0; j < 8; ++j) {
                int k = t * 32 + kg * 8 + j;
                tb.u[j] = (k < INC) ? f2bf(w1s[k * 65 + c]) : (unsigned short)0;
            }
            bf[t] = tb.v;
        }
        f32x4 acc = {0.f, 0.f, 0.f, 0.f};
        acc = __builtin_amdgcn_mfma_f32_16x16x32_bf16(a[0], bf[0], acc, 0, 0, 0);
        acc = __builtin_amdgcn_mfma_f32_16x16x32_bf16(a[1], bf[1], acc, 0, 0, 0);
        acc = __builtin_amdgcn_mfma_f32_16x16x32_bf16(a[2], bf[2], acc, 0, 0, 0);
        unsigned short* cb = hw1s + (size_t)(row0 + kg * 4) * C1 + c;
        #pragma unroll
        for (int i = 0; i < 4; ++i) cb[(size_t)i * C1] = f2bf(acc[i] * dsc[i]);
    }
}

// ---------- gather core: 8-lane group, 16B row fragments, unroll 4 ----------
__device__ __forceinline__ void gather_node(
    const unsigned* __restrict__ csr, int start, int len,
    const unsigned short* __restrict__ vin, int c0,
    float& a0, float& a1, float& a2, float& a3,
    float& a4, float& a5, float& a6, float& a7) {
    int e = 0;
    for (; e + 4 <= len; e += 4) {
        unsigned s0 = csr[start + e + 0];
        unsigned s1 = csr[start + e + 1];
        unsigned s2 = csr[start + e + 2];
        unsigned s3 = csr[start + e + 3];
        uint4 r0 = *(const uint4*)(vin + (size_t)s0 * 64 + c0);
        uint4 r1 = *(const uint4*)(vin + (size_t)s1 * 64 + c0);
        uint4 r2 = *(const uint4*)(vin + (size_t)s2 * 64 + c0);
        uint4 r3 = *(const uint4*)(vin + (size_t)s3 * 64 + c0);
        a0 += (bflo(r0.x) + bflo(r1.x)) + (bflo(r2.x) + bflo(r3.x));
        a1 += (bfhi(r0.x) + bfhi(r1.x)) + (bfhi(r2.x) + bfhi(r3.x));
        a2 += (bflo(r0.y) + bflo(r1.y)) + (bflo(r2.y) + bflo(r3.y));
        a3 += (bfhi(r0.y) + bfhi(r1.y)) + (bfhi(r2.y) + bfhi(r3.y));
        a4 += (bflo(r0.z) + bflo(r1.z)) + (bflo(r2.z) + bflo(r3.z));
        a5 += (bfhi(r0.z) + bfhi(r1.z)) + (bfhi(r2.z) + bfhi(r3.z));
        a6 += (bflo(r0.w) + bflo(r1.w)) + (bflo(r2.w) + bflo(r3.w));
        a7 += (bfhi(r0.w) + bfhi(r1.w)) + (bfhi(r2.w) + bfhi(r3.w));
    }
    for (; e < len; ++e) {
        unsigned s = csr[start + e];
        uint4 ra = *(const uint4*)(vin + (size_t)s * 64 + c0);
        a0 += bflo(ra.x); a1 += bfhi(ra.x);
        a2 += bflo(ra.y); a3 += bfhi(ra.y);
        a4 += bflo(ra.z); a5 += bfhi(ra.z);
        a6 += bflo(ra.w); a7 += bfhi(ra.w);
    }
}

// ---------- aggregate kernels (8 lanes/node, 32 nodes/block) ----------
// EP=1: out = bf16(relu(dinv*(acc+self) + b1) * dinv);  EP=2: out = bf16(dinv*(acc+self))
template <int EP>
__global__ __launch_bounds__(256) void agg_csr_kernel(
    const unsigned* __restrict__ csr, const int* __restrict__ rs,
    const float* __restrict__ dinv, const unsigned short* __restrict__ vin,
    const float* __restrict__ bias, unsigned short* __restrict__ vout) {
    int node = blockIdx.x * 32 + (threadIdx.x >> 3);
    int l = threadIdx.x & 7;
    int c0 = l * 8;
    int start = rs[node], len = rs[node + 1] - start;
    float a0 = 0.f, a1 = 0.f, a2 = 0.f, a3 = 0.f, a4 = 0.f, a5 = 0.f, a6 = 0.f, a7 = 0.f;
    gather_node(csr, start, len, vin, c0, a0, a1, a2, a3, a4, a5, a6, a7);
    uint4 sv = *(const uint4*)(vin + (size_t)node * 64 + c0);
    a0 += bflo(sv.x); a1 += bfhi(sv.x);
    a2 += bflo(sv.y); a3 += bfhi(sv.y);
    a4 += bflo(sv.z); a5 += bfhi(sv.z);
    a6 += bflo(sv.w); a7 += bfhi(sv.w);
    float d = dinv[node];
    if (EP == 1) {
        a0 = fmaxf(a0 * d + bias[c0 + 0], 0.f) * d;
        a1 = fmaxf(a1 * d + bias[c0 + 1], 0.f) * d;
        a2 = fmaxf(a2 * d + bias[c0 + 2], 0.f) * d;
        a3 = fmaxf(a3 * d + bias[c0 + 3], 0.f) * d;
        a4 = fmaxf(a4 * d + bias[c0 + 4], 0.f) * d;
        a5 = fmaxf(a5 * d + bias[c0 + 5], 0.f) * d;
        a6 = fmaxf(a6 * d + bias[c0 + 6], 0.f) * d;
        a7 = fmaxf(a7 * d + bias[c0 + 7], 0.f) * d;
    } else {
        a0 *= d; a1 *= d; a2 *= d; a3 *= d; a4 *= d; a5 *= d; a6 *= d; a7 *= d;
    }
    uint4 o;
    o.x = (unsigned)f2bf(a0) | ((unsigned)f2bf(a1) << 16);
    o.y = (unsigned)f2bf(a2) | ((unsigned)f2bf(a3) << 16);
    o.z = (unsigned)f2bf(a4) | ((unsigned)f2bf(a5) << 16);
    o.w = (unsigned)f2bf(a6) | ((unsigned)f2bf(a7) << 16);
    *(uint4*)(vout + (size_t)node * 64 + c0) = o;
}

// ---------- gemm2: h2 = bf16(relu(aggH @ W2 + b2)); W2 f32 LDS (stride 129) ----------
__global__ __launch_bounds__(256) void gemm2_mfma(const unsigned short* __restrict__ aggH,
                                                  const float* __restrict__ W2,
                                                  const float* __restrict__ b2,
                                                  unsigned short* __restrict__ h2) {
    __shared__ float w2s[C1 * 129];   // 33024 B
    for (int i = threadIdx.x; i < (C1 * C2) / 2; i += 256) {
        float2 w = ((const float2*)W2)[i];
        int k = (i * 2) >> 7, c = (i * 2) & 127;
        w2s[k * 129 + c] = w.x;
        w2s[k * 129 + c + 1] = w.y;
    }
    __syncthreads();
    int wave = threadIdx.x >> 6, lane = threadIdx.x & 63;
    int r = lane & 15, kg = lane >> 4;
    int row0 = blockIdx.x * 64 + wave * 16;
    const unsigned short* arow = aggH + (size_t)(row0 + r) * 64 + kg * 8;
    bf16x8 a0 = *(const bf16x8*)(arow);
    bf16x8 a1 = *(const bf16x8*)(arow + 32);
    #pragma unroll
    for (int nt = 0; nt < 8; ++nt) {
        int col = nt * 16 + r;
        bf16x8 b0, b1;
        {
            union { bf16x8 v; unsigned short u[8]; } tb;
            #pragma unroll
            for (int j = 0; j < 8; ++j) tb.u[j] = f2bf(w2s[(kg * 8 + j) * 129 + col]);
            b0 = tb.v;
            #pragma unroll
            for (int j = 0; j < 8; ++j) tb.u[j] = f2bf(w2s[(32 + kg * 8 + j) * 129 + col]);
            b1 = tb.v;
        }
        f32x4 acc = {0.f, 0.f, 0.f, 0.f};
        acc = __builtin_amdgcn_mfma_f32_16x16x32_bf16(a0, b0, acc, 0, 0, 0);
        acc = __builtin_amdgcn_mfma_f32_16x16x32_bf16(a1, b1, acc, 0, 0, 0);
        float bb = b2[col];
        unsigned short* cb = h2 + (size_t)(row0 + kg * 4) * C2 + col;
        #pragma unroll
        for (int i = 0; i < 4; ++i) cb[(size_t)i * C2] = f2bf(fmaxf(acc[i] + bb, 0.f));
    }
}

// ---------- fused mean-pool + final FC ----------
__device__ __forceinline__ int lbound(const int* __restrict__ a, int n, int key) {
    int lo = 0, hi = n;
    while (lo < hi) {
        int mid = (lo + hi) >> 1;
        if (a[mid] < key) lo = mid + 1; else hi = mid;
    }
    return lo;
}

__global__ __launch_bounds__(256) void pool_fc_kernel(const unsigned short* __restrict__ h2,
                                                      const int* __restrict__ batch,
                                                      const float* __restrict__ fcw,
                                                      const float* __restrict__ fcb,
                                                      float* __restrict__ out) {
    __shared__ float ps[512];
    __shared__ float pr[128];
    int g = blockIdx.x;
    int lo = lbound(batch, NN, g);
    int hi = lbound(batch, NN, g + 1);
    int cnt = hi - lo;
    int rg = threadIdx.x >> 6;
    int p = threadIdx.x & 63;
    float s0 = 0.f, s1 = 0.f;
    for (int r = lo + rg; r < hi; r += 4) {
        unsigned v = *(const unsigned*)(h2 + (size_t)r * C2 + p * 2);
        s0 += bflo(v);
        s1 += bfhi(v);
    }
    ps[threadIdx.x * 2 + 0] = s0;
    ps[threadIdx.x * 2 + 1] = s1;
    __syncthreads();
    if (threadIdx.x < 64) {
        float inv = 1.0f / (float)((cnt > 0) ? cnt : 1);
        int t = threadIdx.x;
        float r0 = 0.f, r1 = 0.f;
        #pragma unroll
        for (int k = 0; k < 4; ++k) {
            r0 += ps[(k * 64 + t) * 2 + 0];
            r1 += ps[(k * 64 + t) * 2 + 1];
        }
        pr[2 * t + 0] = r0 * inv;
        pr[2 * t + 1] = r1 * inv;
    }
    __syncthreads();
    if (threadIdx.x < 128) {
        int o = threadIdx.x;
        float acc = fcb[o];
        #pragma unroll 8
        for (int k = 0; k < C2; ++k) acc += pr[k] * fcw[k * ODIM + o];
        out[(size_t)g * ODIM + o] = acc;
    }
}

extern "C" void kernel_launch(void* const* d_in, const int* in_sizes, int n_in,
                              void* d_out, int out_size, void* d_ws, size_t ws_size,
                              hipStream_t stream) {
    const float* x   = (const float*)d_in[0];
    const int*   ei  = (const int*)d_in[1];
    const int*   bat = (const int*)d_in[2];
    const float* W1  = (const float*)d_in[3];
    const float* b1  = (const float*)d_in[4];
    const float* W2  = (const float*)d_in[5];
    const float* b2  = (const float*)d_in[6];
    const float* fcw = (const float*)d_in[7];
    const float* fcb = (const float*)d_in[8];
    float* out = (float*)d_out;

    const int* src = ei;        // edge_index[0]
    const int* dst = ei + NE;   // edge_index[1]

    char* ws = (char*)d_ws;
    int* gcursor = (int*)ws;            ws += alignup((size_t)NBKT * 4);
    int* rs      = (int*)ws;            ws += alignup((size_t)(NN + 1) * 4);
    float* dinv  = (float*)ws;          ws += alignup((size_t)NN * 4);
    unsigned short* hw1s = (unsigned short*)ws; ws += alignup((size_t)NN * C1 * 2);
    unsigned short* aggH = hw1s;        // reuse: hw1s dead after agg_csr<1>
    // h2 (51.2MB) aliases [ebuf 25.6 | csr 12.8 | first 12.8 of h1s] -- all dead before gemm2
    unsigned* ebuf = (unsigned*)ws;     ws += alignup((size_t)NBKT * CAP * 4);
    unsigned* csr  = (unsigned*)ws;     ws += alignup((size_t)NE * 4);
    unsigned short* h1s = (unsigned short*)ws;  ws += alignup((size_t)NN * C1 * 2);
    unsigned short* h2 = (unsigned short*)ebuf;
    // total ~91 MB

    // ---- single-pass binning into padded bucket regions ----
    hipMemsetAsync(gcursor, 0, (size_t)NBKT * 4, stream);
    binsort_kernel<<<NBLK, BTH, 0, stream>>>(src, dst, gcursor, ebuf);

    // ---- bucket scan (folded) + degrees + dinv + rs + dense CSR ----
    degcsr_kernel<<<NBKT, 256, 0, stream>>>(ebuf, gcursor, rs, dinv, csr);

    // ---- layer 1: staged MFMA GEMM (in-kernel W1 conversion) then gather ----
    gemm1_mfma<<<NN / 64, 256, 0, stream>>>(x, W1, dinv, hw1s);
    agg_csr_kernel<1><<<NN / 32, 256, 0, stream>>>(csr, rs, dinv, hw1s, b1, h1s);

    // ---- layer 2: aggregate first (linearity), then GEMM + relu -> h2 ----
    agg_csr_kernel<2><<<NN / 32, 256, 0, stream>>>(csr, rs, dinv, h1s, b1, aggH);
    gemm2_mfma<<<NN / 64, 256, 0, stream>>>(aggH, W2, b2, h2);

    // ---- fused mean-pool + FC ----
    pool_fc_kernel<<<NG, 256, 0, stream>>>(h2, bat, fcw, fcb, out);
}